// Round 9
// baseline (8672.747 us; speedup 1.0000x reference)
//
#include <hip/hip_runtime.h>
#include <math.h>

#define NWG 256
#define TPB 256

typedef float v4f __attribute__((ext_vector_type(4)));

constexpr int Bn = 16, Sn = 128, Vn = 32000, DMn = 1024, DSn = 512;
constexpr float DECAYc = 0.6065306597126334f;  // exp(-1/tau), tau=2
constexpr float THRc = 1.0f, EPSc = 1e-5f;

// ---- workspace byte offsets (region sizes identical to R8) ----
constexpr size_t OF_FLAGS  = 0;                                   // 1024 wave-flags * 1KB
constexpr size_t OF_STATES = (size_t)256*4096;                    // [2][16][512]
constexpr size_t OF_E0     = OF_STATES + (size_t)2*16*512*4;      // [16][1024]
constexpr size_t OF_E1     = OF_E0 + (size_t)16*1024*4;
constexpr size_t OF_ENCX   = OF_E1 + (size_t)16*1024*4;           // [128][16][1024] raw enc GEMM
constexpr size_t OF_HS     = OF_ENCX + (size_t)128*16*1024*4;     // [128][16][512]
constexpr size_t OF_WGT    = OF_HS + (size_t)128*16*512*4;        // WgT [2][1024][512]
constexpr size_t OF_WIT    = OF_WGT + (size_t)2*1024*512*4;       // WiT [2][512][1024]
constexpr size_t INIT_BYTES = OF_E0;   // zero flags + states

struct SP {
  const int* ids; const float* emb;
  const float* W_enc; const float* b_enc;
  const float* ln_s_g; const float* ln_s_b;
  const float* Wg; const float* bg;
  const float* ln_e_g; const float* ln_e_b;
  const float* Wi; const float* bi;
};

// LLC-coherent (L1+L2 bypass) accesses: no fences needed anywhere.
__device__ __forceinline__ void st_cg(float* p, float v) {
  __hip_atomic_store(p, v, __ATOMIC_RELAXED, __HIP_MEMORY_SCOPE_AGENT);
}
__device__ __forceinline__ int ld_flag(const int* p) {
  return __hip_atomic_load(p, __ATOMIC_RELAXED, __HIP_MEMORY_SCOPE_AGENT);
}
__device__ __forceinline__ void st_flag(int* p, int v) {
  __hip_atomic_store(p, v, __ATOMIC_RELAXED, __HIP_MEMORY_SCOPE_AGENT);
}

// one butterfly reduce-scatter step: SZ live values -> SZ/2, partner lane ^M.
template<int SZ>
__device__ __forceinline__ void bstep(float* v, bool up, int M) {
  #pragma unroll
  for (int q = 0; q < SZ/2; q++) {
    float lo = v[q], hi = v[q + SZ/2];
    float send = up ? lo : hi;
    float recv = __shfl_xor(send, M);
    v[q] = (up ? hi : lo) + recv;
  }
}

// wave-scope wait: poll 128 producer wave-flags (2 per lane) until >= target.
__device__ __forceinline__ void waitwaves(const int* fl, int l, int target) {
  const int* p0 = fl + (size_t)l * 256;
  const int* p1 = fl + (size_t)(l + 64) * 256;
  for (;;) {
    int a = ld_flag(p0);
    int b = ld_flag(p1);
    if (__all((a >= target) && (b >= target))) break;
  }
  asm volatile("" ::: "memory");
}
// wave-scope publish: drain my stores (wave-level), lane 0 stores flag.
__device__ __forceinline__ void pubwave(int* myflag, int l, int epoch) {
  asm volatile("s_waitcnt vmcnt(0)" ::: "memory");
  if (l == 0) st_flag(myflag, epoch);
}

// ---------------- gen step: K=512 (Kc=8/lane), 8 o/wave, wave-autonomous ----
template<bool FIRST>
__device__ __forceinline__ void gen_step(
    const float* __restrict__ Wbase,                 // WgT + j*DMn*DSn
    const float (&lg)[8], const float (&lb)[8], float biasv,
    const float* __restrict__ src,                   // states[j]
    const int* __restrict__ othf, int target,
    int* __restrict__ myflag, int epoch,
    float& mreg, float& btReg, float eEv,
    float* __restrict__ errw,
    int o0w, int o, int bg, int grp, int l)
{
  // ---- W loads: read-only, issued before the poll (latency hides under it) ----
  v4f wv[8][2];
  #pragma unroll
  for (int i = 0; i < 8; i++) {
    const v4f* wp = (const v4f*)(Wbase + (size_t)(o0w + i)*DSn + l*8);
    wv[i][0] = wp[0]; wv[i][1] = wp[1];
  }
  // ---- wait for producers ----
  waitwaves(othf, l, target);
  // ---- src loads (LLC-coherent) ----
  v4f x[4][2];
  #pragma unroll
  for (int r = 0; r < 4; r++) {
    const float* sp = src + (size_t)(grp*4 + r)*DSn + l*8;
    asm volatile("global_load_dwordx4 %0, %1, off sc0 sc1" : "=v"(x[r][0]) : "v"(sp));
    asm volatile("global_load_dwordx4 %0, %1, off sc0 sc1" : "=v"(x[r][1]) : "v"(sp + 4));
  }
  asm volatile("s_waitcnt vmcnt(0)" ::: "memory");
  __builtin_amdgcn_sched_barrier(0);
  // ---- LayerNorm, 4 rows in parallel (same add order as R8) ----
  float s1[4] = {0.f,0.f,0.f,0.f}, s2[4], mean[4], rstd[4];
  #pragma unroll
  for (int r = 0; r < 4; r++)
    #pragma unroll
    for (int e = 0; e < 4; e++) { s1[r] += x[r][0][e]; s1[r] += x[r][1][e]; }
  #pragma unroll
  for (int off = 32; off; off >>= 1)
    #pragma unroll
    for (int r = 0; r < 4; r++) s1[r] += __shfl_xor(s1[r], off);
  #pragma unroll
  for (int r = 0; r < 4; r++) { mean[r] = s1[r] * (1.0f/512.0f); s2[r] = 0.f; }
  #pragma unroll
  for (int r = 0; r < 4; r++)
    #pragma unroll
    for (int e = 0; e < 4; e++) {
      float d0 = x[r][0][e] - mean[r]; s2[r] += d0*d0;
      float d1 = x[r][1][e] - mean[r]; s2[r] += d1*d1;
    }
  #pragma unroll
  for (int off = 32; off; off >>= 1)
    #pragma unroll
    for (int r = 0; r < 4; r++) s2[r] += __shfl_xor(s2[r], off);
  #pragma unroll
  for (int r = 0; r < 4; r++) rstd[r] = 1.0f / sqrtf(s2[r]*(1.0f/512.0f) + EPSc);
  #pragma unroll
  for (int r = 0; r < 4; r++)
    #pragma unroll
    for (int e = 0; e < 4; e++) {
      x[r][0][e] = (x[r][0][e] - mean[r])*rstd[r]*lg[e]   + lb[e];
      x[r][1][e] = (x[r][1][e] - mean[r])*rstd[r]*lg[4+e] + lb[4+e];
    }
  // ---- GEMM partials (identical FMA order to R8) ----
  float v[32];
  #pragma unroll
  for (int n = 0; n < 32; n++) v[n] = 0.f;
  #pragma unroll
  for (int b = 0; b < 4; b++)
    #pragma unroll
    for (int i = 0; i < 8; i++) {
      float a = v[i*4 + b];
      #pragma unroll
      for (int e = 0; e < 4; e++) a = fmaf(x[b][0][e], wv[i][0][e], a);
      #pragma unroll
      for (int e = 0; e < 4; e++) a = fmaf(x[b][1][e], wv[i][1][e], a);
      v[i*4 + b] = a;
    }
  // ---- butterfly reduce-scatter (NV=32) ----
  bstep<32>(v, (l & 32) != 0, 32);
  bstep<16>(v, (l & 16) != 0, 16);
  bstep<8> (v, (l &  8) != 0,  8);
  bstep<4> (v, (l &  4) != 0,  4);
  bstep<2> (v, (l &  2) != 0,  2);
  v[0] += __shfl_xor(v[0], 1);
  // ---- bias + LIF + err store + publish ----
  const float val = v[0] + biasv;
  const float mt = mreg * DECAYc + val;
  const float spk = (mt >= THRc) ? 1.f : 0.f;
  mreg = mt * (1.f - spk);
  const float ne = (FIRST ? eEv : btReg) - spk;
  btReg = ne;
  if ((l & 1) == 0) st_cg(errw + (size_t)bg*DMn + o, ne);
  pubwave(myflag, l, epoch);
}

// ---------------- inf step: K=1024 (Kc=16/lane), 4 o/wave, wave-autonomous ----
__device__ __forceinline__ void inf_step(
    const float* __restrict__ Wbase,                 // WiT + j*DSn*DMn
    const float* __restrict__ lngp, const float* __restrict__ lnbp, float biasv,
    const float* __restrict__ src,                   // err[j]
    const int* __restrict__ othf, int target,
    int* __restrict__ myflag, int epoch,
    float& mreg, float& streg,
    float* __restrict__ stw, float* __restrict__ hsw,
    int o0w, int o, int bg, int grp, int l)
{
  // ---- W + LN params: read-only, issued before the poll ----
  v4f wv[4][4];
  #pragma unroll
  for (int i = 0; i < 4; i++) {
    const v4f* wp = (const v4f*)(Wbase + (size_t)(o0w + i)*DMn + l*16);
    #pragma unroll
    for (int q = 0; q < 4; q++) wv[i][q] = wp[q];
  }
  v4f lgv[4], lbv[4];
  {
    const v4f* g = (const v4f*)(lngp + l*16);
    const v4f* c = (const v4f*)(lnbp + l*16);
    #pragma unroll
    for (int q = 0; q < 4; q++) { lgv[q] = g[q]; lbv[q] = c[q]; }
  }
  // ---- wait for producers ----
  waitwaves(othf, l, target);
  // ---- src loads (LLC-coherent) ----
  v4f x[4][4];
  #pragma unroll
  for (int r = 0; r < 4; r++) {
    const float* sp = src + (size_t)(grp*4 + r)*DMn + l*16;
    #pragma unroll
    for (int q = 0; q < 4; q++)
      asm volatile("global_load_dwordx4 %0, %1, off sc0 sc1" : "=v"(x[r][q]) : "v"(sp + 4*q));
  }
  asm volatile("s_waitcnt vmcnt(0)" ::: "memory");
  __builtin_amdgcn_sched_barrier(0);
  // ---- LayerNorm, 4 rows in parallel (same add order as R8) ----
  float s1[4] = {0.f,0.f,0.f,0.f}, s2[4], mean[4], rstd[4];
  #pragma unroll
  for (int r = 0; r < 4; r++)
    #pragma unroll
    for (int q = 0; q < 4; q++)
      #pragma unroll
      for (int e = 0; e < 4; e++) s1[r] += x[r][q][e];
  #pragma unroll
  for (int off = 32; off; off >>= 1)
    #pragma unroll
    for (int r = 0; r < 4; r++) s1[r] += __shfl_xor(s1[r], off);
  #pragma unroll
  for (int r = 0; r < 4; r++) { mean[r] = s1[r] * (1.0f/1024.0f); s2[r] = 0.f; }
  #pragma unroll
  for (int r = 0; r < 4; r++)
    #pragma unroll
    for (int q = 0; q < 4; q++)
      #pragma unroll
      for (int e = 0; e < 4; e++) { float d = x[r][q][e] - mean[r]; s2[r] += d*d; }
  #pragma unroll
  for (int off = 32; off; off >>= 1)
    #pragma unroll
    for (int r = 0; r < 4; r++) s2[r] += __shfl_xor(s2[r], off);
  #pragma unroll
  for (int r = 0; r < 4; r++) rstd[r] = 1.0f / sqrtf(s2[r]*(1.0f/1024.0f) + EPSc);
  #pragma unroll
  for (int r = 0; r < 4; r++)
    #pragma unroll
    for (int q = 0; q < 4; q++)
      #pragma unroll
      for (int e = 0; e < 4; e++)
        x[r][q][e] = (x[r][q][e] - mean[r])*rstd[r]*lgv[q][e] + lbv[q][e];
  // ---- GEMM partials (identical FMA order to R8) ----
  float v[16];
  #pragma unroll
  for (int n = 0; n < 16; n++) v[n] = 0.f;
  #pragma unroll
  for (int b = 0; b < 4; b++)
    #pragma unroll
    for (int i = 0; i < 4; i++) {
      float a = v[i*4 + b];
      #pragma unroll
      for (int q = 0; q < 4; q++)
        #pragma unroll
        for (int e = 0; e < 4; e++) a = fmaf(x[b][q][e], wv[i][q][e], a);
      v[i*4 + b] = a;
    }
  // ---- butterfly reduce-scatter (NV=16) ----
  bstep<16>(v, (l & 32) != 0, 32);
  bstep<8> (v, (l & 16) != 0, 16);
  bstep<4> (v, (l &  8) != 0,  8);
  bstep<2> (v, (l &  4) != 0,  4);
  v[0] += __shfl_xor(v[0], 2);
  v[0] += __shfl_xor(v[0], 1);
  // ---- bias + LIF + state store + publish ----
  const float val = v[0] + biasv;
  const float mt = mreg * DECAYc + val;
  const float spk = (mt >= THRc) ? 1.f : 0.f;
  mreg = mt * (1.f - spk);
  const float ns = streg + spk;
  streg = ns;
  if ((l & 3) == 0) {
    st_cg(stw + (size_t)bg*DSn + o, ns);
    if (hsw) hsw[(size_t)bg*DSn + o] = ns;
  }
  pubwave(myflag, l, epoch);
}

__global__ void __launch_bounds__(TPB, 1) snn_scan(SP p, char* __restrict__ ws)
{
  extern __shared__ float Xpad[];  // 84 KiB dynamic, unused -> pins 1 WG/CU
  (void)Xpad;
  const int wgg = blockIdx.x, tid = threadIdx.x;
  const int grp = wgg >> 6, wgl = wgg & 63;
  const int w = tid >> 6, l = tid & 63;
  int* flags  = (int*)(ws + OF_FLAGS);
  int* myflag = flags + (size_t)(((grp*64 + wgl) << 2) + w) * 256;
  float* states = (float*)(ws + OF_STATES);
  float* e0     = (float*)(ws + OF_E0);
  float* e1     = (float*)(ws + OF_E1);
  const float* encX = (const float*)(ws + OF_ENCX);
  float* hs     = (float*)(ws + OF_HS);
  const float* WgT = (const float*)(ws + OF_WGT);
  const float* WiT = (const float*)(ws + OF_WIT);
  float* st0 = states;
  float* st1 = states + (size_t)Bn*DSn;

  if (wgl < 32) {
    // ---------------- generative pipeline (per-wave autonomous) ----------------
    const int* othf = flags + (size_t)(grp*256 + 128) * 256;  // inf wave flags
    const int o0 = wgl * 32, o0w = o0 + w*8;
    const int o_i = (l >> 3) & 7, b_loc = (l >> 1) & 3;
    const int o = o0w + o_i, bg = grp*4 + b_loc;
    const float* WA = WgT;
    const float* WB = WgT + (size_t)DMn*DSn;
    float lgA[8], lbA[8], lgB[8], lbB[8];
    {
      const v4f* g0 = (const v4f*)(p.ln_s_g + l*8);
      const v4f* c0 = (const v4f*)(p.ln_s_b + l*8);
      const v4f* g1 = (const v4f*)(p.ln_s_g + DSn + l*8);
      const v4f* c1 = (const v4f*)(p.ln_s_b + DSn + l*8);
      v4f ga = g0[0], gb = g0[1], ba = c0[0], bb = c0[1];
      v4f gc = g1[0], gd = g1[1], bc = c1[0], bd = c1[1];
      #pragma unroll
      for (int e = 0; e < 4; e++) {
        lgA[e] = ga[e]; lgA[4+e] = gb[e]; lbA[e] = ba[e]; lbA[4+e] = bb[e];
        lgB[e] = gc[e]; lgB[4+e] = gd[e]; lbB[e] = bc[e]; lbB[4+e] = bd[e];
      }
    }
    const float biasA = p.bg[o], biasB = p.bg[DMn + o];
    float encMem = 0.f, btReg = 0.f, genMemA = 0.f, genMemB = 0.f;

    for (int s = 0; s < Sn; s++) {
      const int s8 = s*8;
      // inline encoder LIF (token-static input, plain cached load)
      const float ex = encX[(size_t)s*Bn*DMn + (size_t)bg*DMn + o];
      const float emt = encMem*DECAYc + ex;
      const float esp = (emt >= THRc) ? 1.f : 0.f;
      encMem = emt * (1.f - esp);
      gen_step<true >(WA, lgA, lbA, biasA, st0, othf, s8-1, myflag, s8+1,
                      genMemA, btReg, esp, e0, o0w, o, bg, grp, l);
      gen_step<false>(WB, lgB, lbB, biasB, st1, othf, s8+0, myflag, s8+2,
                      genMemB, btReg, 0.f, e1, o0w, o, bg, grp, l);
      gen_step<false>(WA, lgA, lbA, biasA, st0, othf, s8+1, myflag, s8+3,
                      genMemA, btReg, 0.f, e0, o0w, o, bg, grp, l);
      gen_step<false>(WB, lgB, lbB, biasB, st1, othf, s8+2, myflag, s8+4,
                      genMemB, btReg, 0.f, e1, o0w, o, bg, grp, l);
      gen_step<false>(WA, lgA, lbA, biasA, st0, othf, s8+3, myflag, s8+5,
                      genMemA, btReg, 0.f, e0, o0w, o, bg, grp, l);
      gen_step<false>(WB, lgB, lbB, biasB, st1, othf, s8+4, myflag, s8+6,
                      genMemB, btReg, 0.f, e1, o0w, o, bg, grp, l);
      gen_step<false>(WA, lgA, lbA, biasA, st0, othf, s8+5, myflag, s8+7,
                      genMemA, btReg, 0.f, e0, o0w, o, bg, grp, l);
      gen_step<false>(WB, lgB, lbB, biasB, st1, othf, s8+6, myflag, s8+8,
                      genMemB, btReg, 0.f, e1, o0w, o, bg, grp, l);
    }
  } else {
    // ---------------- inference pipeline (per-wave autonomous) ----------------
    const int* othf = flags + (size_t)(grp*256) * 256;        // gen wave flags
    const int o0 = (wgl - 32) * 16, o0w = o0 + w*4;
    const int o_i = (l >> 4) & 3, b_loc = (l >> 2) & 3;
    const int o = o0w + o_i, bg = grp*4 + b_loc;
    const float* WA = WiT;
    const float* WB = WiT + (size_t)DSn*DMn;
    const float biasA = p.bi[o], biasB = p.bi[DSn + o];
    float infMemA = 0.f, infMemB = 0.f, stRegA = 0.f, stRegB = 0.f;

    for (int s = 0; s < Sn; s++) {
      const int s8 = s*8;
      inf_step(WA, p.ln_e_g,       p.ln_e_b,       biasA, e0, othf, s8+1, myflag, s8+1,
               infMemA, stRegA, st0, nullptr, o0w, o, bg, grp, l);
      inf_step(WB, p.ln_e_g + DMn, p.ln_e_b + DMn, biasB, e1, othf, s8+2, myflag, s8+2,
               infMemB, stRegB, st1, nullptr, o0w, o, bg, grp, l);
      inf_step(WA, p.ln_e_g,       p.ln_e_b,       biasA, e0, othf, s8+3, myflag, s8+3,
               infMemA, stRegA, st0, nullptr, o0w, o, bg, grp, l);
      inf_step(WB, p.ln_e_g + DMn, p.ln_e_b + DMn, biasB, e1, othf, s8+4, myflag, s8+4,
               infMemB, stRegB, st1, nullptr, o0w, o, bg, grp, l);
      inf_step(WA, p.ln_e_g,       p.ln_e_b,       biasA, e0, othf, s8+5, myflag, s8+5,
               infMemA, stRegA, st0, nullptr, o0w, o, bg, grp, l);
      inf_step(WB, p.ln_e_g + DMn, p.ln_e_b + DMn, biasB, e1, othf, s8+6, myflag, s8+6,
               infMemB, stRegB, st1, nullptr, o0w, o, bg, grp, l);
      inf_step(WA, p.ln_e_g,       p.ln_e_b,       biasA, e0, othf, s8+7, myflag, s8+7,
               infMemA, stRegA, st0, nullptr, o0w, o, bg, grp, l);
      inf_step(WB, p.ln_e_g + DMn, p.ln_e_b + DMn, biasB, e1, othf, s8+8, myflag, s8+8,
               infMemB, stRegB, st1, hs + (size_t)s*Bn*DSn, o0w, o, bg, grp, l);
    }
  }
}

// tiled transpose: in [K][O] -> out [O][K]
__global__ void __launch_bounds__(256) transpose_k(
    const float* __restrict__ in, float* __restrict__ out, int K, int O)
{
  __shared__ float t[32][33];
  const int ob = blockIdx.x * 32, kb = blockIdx.y * 32;
  const int x = threadIdx.x, y = threadIdx.y;
  #pragma unroll
  for (int i = 0; i < 32; i += 8) t[y + i][x] = in[(size_t)(kb + y + i)*O + ob + x];
  __syncthreads();
  #pragma unroll
  for (int i = 0; i < 32; i += 8) out[(size_t)(ob + y + i)*K + kb + x] = t[x][y + i];
}

// encX = gather(emb, ids) @ W_enc + b_enc   (M=2048, K=1024, N=1024) — raw, no LIF
__global__ void __launch_bounds__(256) enc_gemm(
    const int* __restrict__ ids, const float* __restrict__ emb,
    const float* __restrict__ We, const float* __restrict__ be,
    float* __restrict__ encX)
{
  __shared__ float As[32][128];
  __shared__ float Bs[32][128];
  __shared__ int rowid[128];
  const int tid = threadIdx.x;
  const int ntile = blockIdx.x * 128;
  const int mtile = blockIdx.y * 128;
  if (tid < 128) {
    int m = mtile + tid;                  // m = s*16 + b
    rowid[tid] = ids[(m & 15)*Sn + (m >> 4)];
  }
  __syncthreads();
  const int tx = tid & 15, ty = tid >> 4;
  float acc[8][8];
  #pragma unroll
  for (int i = 0; i < 8; i++)
    #pragma unroll
    for (int q = 0; q < 8; q++) acc[i][q] = 0.f;

  for (int kb = 0; kb < 32; kb++) {
    #pragma unroll
    for (int r = 0; r < 4; r++) {
      int idx = tid + r*256;
      int m = idx >> 3, kq = idx & 7;
      float4 a = *(const float4*)(emb + (size_t)rowid[m]*DMn + kb*32 + kq*4);
      As[kq*4+0][m] = a.x; As[kq*4+1][m] = a.y;
      As[kq*4+2][m] = a.z; As[kq*4+3][m] = a.w;
    }
    #pragma unroll
    for (int r = 0; r < 4; r++) {
      int idx = tid + r*256;
      int k = idx >> 5, nq = idx & 31;
      *(float4*)(&Bs[k][nq*4]) =
          *(const float4*)(We + (size_t)(kb*32 + k)*DMn + ntile + nq*4);
    }
    __syncthreads();
    #pragma unroll
    for (int k = 0; k < 32; k++) {
      float4 a0 = *(float4*)(&As[k][ty*8]);
      float4 a1 = *(float4*)(&As[k][ty*8+4]);
      float4 b0 = *(float4*)(&Bs[k][tx*8]);
      float4 b1 = *(float4*)(&Bs[k][tx*8+4]);
      float av[8] = {a0.x,a0.y,a0.z,a0.w,a1.x,a1.y,a1.z,a1.w};
      float bv[8] = {b0.x,b0.y,b0.z,b0.w,b1.x,b1.y,b1.z,b1.w};
      #pragma unroll
      for (int i = 0; i < 8; i++)
        #pragma unroll
        for (int q = 0; q < 8; q++) acc[i][q] += av[i]*bv[q];
    }
    __syncthreads();
  }
  const float* bop = be + ntile + tx*8;
  float4 bv0 = *(const float4*)bop;
  float4 bv1 = *(const float4*)(bop + 4);
  #pragma unroll
  for (int i = 0; i < 8; i++) {
    int m = mtile + ty*8 + i;
    float* op = encX + (size_t)m*DMn + ntile + tx*8;
    float4 v0 = make_float4(acc[i][0]+bv0.x, acc[i][1]+bv0.y,
                            acc[i][2]+bv0.z, acc[i][3]+bv0.w);
    float4 v1 = make_float4(acc[i][4]+bv1.x, acc[i][5]+bv1.y,
                            acc[i][6]+bv1.z, acc[i][7]+bv1.w);
    *(float4*)op = v0;
    *(float4*)(op + 4) = v1;
  }
}

// logits = hs @ W_out + b_out, fp32, 128x128 tile, 8x8 microtile
__global__ void __launch_bounds__(256) out_gemm(
    const float* __restrict__ hs, const float* __restrict__ Wo,
    const float* __restrict__ bo, float* __restrict__ out)
{
  __shared__ float As[32][128];
  __shared__ float Bs[32][128];
  const int tid = threadIdx.x;
  const int ntile = blockIdx.x * 128;
  const int mtile = blockIdx.y * 128;
  const int tx = tid & 15, ty = tid >> 4;
  float acc[8][8];
  #pragma unroll
  for (int i = 0; i < 8; i++)
    #pragma unroll
    for (int q = 0; q < 8; q++) acc[i][q] = 0.f;

  for (int kb = 0; kb < 16; kb++) {
    #pragma unroll
    for (int r = 0; r < 4; r++) {
      int idx = tid + r*256;
      int m = idx >> 3, kq = idx & 7;
      float4 a = *(const float4*)(hs + (size_t)(mtile + m)*512 + kb*32 + kq*4);
      As[kq*4+0][m] = a.x; As[kq*4+1][m] = a.y;
      As[kq*4+2][m] = a.z; As[kq*4+3][m] = a.w;
    }
    #pragma unroll
    for (int r = 0; r < 4; r++) {
      int idx = tid + r*256;
      int k = idx >> 5, nq = idx & 31;
      *(float4*)(&Bs[k][nq*4]) =
          *(const float4*)(Wo + (size_t)(kb*32 + k)*Vn + ntile + nq*4);
    }
    __syncthreads();
    #pragma unroll
    for (int k = 0; k < 32; k++) {
      float4 a0 = *(float4*)(&As[k][ty*8]);
      float4 a1 = *(float4*)(&As[k][ty*8+4]);
      float4 b0 = *(float4*)(&Bs[k][tx*8]);
      float4 b1 = *(float4*)(&Bs[k][tx*8+4]);
      float av[8] = {a0.x,a0.y,a0.z,a0.w,a1.x,a1.y,a1.z,a1.w};
      float bv[8] = {b0.x,b0.y,b0.z,b0.w,b1.x,b1.y,b1.z,b1.w};
      #pragma unroll
      for (int i = 0; i < 8; i++)
        #pragma unroll
        for (int q = 0; q < 8; q++) acc[i][q] += av[i]*bv[q];
    }
    __syncthreads();
  }
  const float* bop = bo + ntile + tx*8;
  float4 bv0 = *(const float4*)bop;
  float4 bv1 = *(const float4*)(bop + 4);
  #pragma unroll
  for (int i = 0; i < 8; i++) {
    int m = mtile + ty*8 + i;            // m = s*16 + b
    float* op = out + ((size_t)(m & 15)*Sn + (m >> 4))*Vn + ntile + tx*8;
    float4 v0 = make_float4(acc[i][0]+bv0.x, acc[i][1]+bv0.y,
                            acc[i][2]+bv0.z, acc[i][3]+bv0.w);
    float4 v1 = make_float4(acc[i][4]+bv1.x, acc[i][5]+bv1.y,
                            acc[i][6]+bv1.z, acc[i][7]+bv1.w);
    *(float4*)op = v0;
    *(float4*)(op + 4) = v1;
  }
}

extern "C" void kernel_launch(void* const* d_in, const int* in_sizes, int n_in,
                              void* d_out, int out_size, void* d_ws, size_t ws_size,
                              hipStream_t stream) {
  (void)in_sizes; (void)n_in; (void)out_size; (void)ws_size;
  SP p;
  p.ids    = (const int*)  d_in[0];
  p.emb    = (const float*)d_in[1];
  p.W_enc  = (const float*)d_in[2];
  p.b_enc  = (const float*)d_in[3];
  p.ln_s_g = (const float*)d_in[4];
  p.ln_s_b = (const float*)d_in[5];
  p.Wg     = (const float*)d_in[6];
  p.bg     = (const float*)d_in[7];
  p.ln_e_g = (const float*)d_in[8];
  p.ln_e_b = (const float*)d_in[9];
  p.Wi     = (const float*)d_in[10];
  p.bi     = (const float*)d_in[11];
  const float* Wo = (const float*)d_in[12];
  const float* bo = (const float*)d_in[13];

  char* ws = (char*)d_ws;
  float* WgT  = (float*)(ws + OF_WGT);
  float* WiT  = (float*)(ws + OF_WIT);
  float* encX = (float*)(ws + OF_ENCX);
  float* hs   = (float*)(ws + OF_HS);

  hipMemsetAsync(ws, 0, INIT_BYTES, stream);   // flags + states = 0

  hipLaunchKernelGGL(transpose_k, dim3(32, 16), dim3(32, 8), 0, stream,
                     p.Wg, WgT, 512, 1024);
  hipLaunchKernelGGL(transpose_k, dim3(32, 16), dim3(32, 8), 0, stream,
                     p.Wg + (size_t)512*1024, WgT + (size_t)1024*512, 512, 1024);
  hipLaunchKernelGGL(transpose_k, dim3(16, 32), dim3(32, 8), 0, stream,
                     p.Wi, WiT, 1024, 512);
  hipLaunchKernelGGL(transpose_k, dim3(16, 32), dim3(32, 8), 0, stream,
                     p.Wi + (size_t)1024*512, WiT + (size_t)512*1024, 1024, 512);

  hipLaunchKernelGGL(enc_gemm, dim3(DMn/128, 2048/128), dim3(256), 0, stream,
                     p.ids, p.emb, p.W_enc, p.b_enc, encX);

  hipLaunchKernelGGL(snn_scan, dim3(NWG), dim3(TPB), 86016, stream, p, ws);

  hipLaunchKernelGGL(out_gemm, dim3(Vn/128, 2048/128), dim3(256), 0, stream,
                     hs, Wo, bo, (float*)d_out);
}

// Round 12
// 6443.449 us; speedup vs baseline: 1.3460x; 1.3460x over previous
//
#include <hip/hip_runtime.h>
#include <math.h>

#define NWG 256
#define TPB 256

typedef float v4f __attribute__((ext_vector_type(4)));

constexpr int Bn = 16, Sn = 128, Vn = 32000, DMn = 1024, DSn = 512;
constexpr float DECAYc = 0.6065306597126334f;  // exp(-1/tau), tau=2
constexpr float THRc = 1.0f, EPSc = 1e-5f;

// ---- workspace byte offsets ----
constexpr size_t OF_FLAGS  = 0;                                   // 256 role-flags * 1KB
constexpr size_t OF_STATES = (size_t)256*4096;                    // [2][16][512]
constexpr size_t OF_E0     = OF_STATES + (size_t)2*16*512*4;      // [16][1024]
constexpr size_t OF_E1     = OF_E0 + (size_t)16*1024*4;
constexpr size_t OF_ENCX   = OF_E1 + (size_t)16*1024*4;           // [128][16][1024] raw enc GEMM
constexpr size_t OF_HS     = OF_ENCX + (size_t)128*16*1024*4;     // [128][16][512]
constexpr size_t OF_WGT    = OF_HS + (size_t)128*16*512*4;        // WgT [2][1024][512]
constexpr size_t OF_WIT    = OF_WGT + (size_t)2*1024*512*4;       // WiT [2][512][1024]
constexpr size_t INIT_BYTES = OF_E0;   // zero flags + states

struct SP {
  const int* ids; const float* emb;
  const float* W_enc; const float* b_enc;
  const float* ln_s_g; const float* ln_s_b;
  const float* Wg; const float* bg;
  const float* ln_e_g; const float* ln_e_b;
  const float* Wi; const float* bi;
};

// Proven primitives (R5-R8): LLC-coherent via __hip_atomic relaxed agent /
// sc0 sc1 asm loads. No fences anywhere.
__device__ __forceinline__ void st_cg(float* p, float v) {
  __hip_atomic_store(p, v, __ATOMIC_RELAXED, __HIP_MEMORY_SCOPE_AGENT);
}
__device__ __forceinline__ int ld_flag(const int* p) {
  return __hip_atomic_load(p, __ATOMIC_RELAXED, __HIP_MEMORY_SCOPE_AGENT);
}
__device__ __forceinline__ void st_flag(int* p, int v) {
  __hip_atomic_store(p, v, __ATOMIC_RELAXED, __HIP_MEMORY_SCOPE_AGENT);
}
__device__ __forceinline__ v4f ldx4(const float* p) {
  v4f r;
  asm volatile("global_load_dwordx4 %0, %1, off sc0 sc1" : "=v"(r) : "v"(p));
  return r;
}

// one butterfly reduce-scatter step: SZ live values -> SZ/2, partner lane ^M.
template<int SZ>
__device__ __forceinline__ void bstep(float* v, bool up, int M) {
  #pragma unroll
  for (int q = 0; q < SZ/2; q++) {
    float lo = v[q], hi = v[q + SZ/2];
    float send = up ? lo : hi;
    float recv = __shfl_xor(send, M);
    v[q] = (up ? hi : lo) + recv;
  }
}

// wait: lanes 0..15 poll the 16 producer-role flags, then gate the WG (R8 mech).
__device__ __forceinline__ void waitrole(const int* base, int tid, int target) {
  if (tid < 16) {
    const int* p = base + (size_t)tid * 256;
    while (ld_flag(p) < target) { }
  }
  asm volatile("" ::: "memory");
  __syncthreads();
}
// publish: each wave drains its stores, WG barrier, tid0 stores epoch (R8 mech).
__device__ __forceinline__ void pubrole(int* myflag, int tid, int epoch) {
  asm volatile("s_waitcnt vmcnt(0)" ::: "memory");
  __syncthreads();
  if (tid == 0) st_flag(myflag, epoch);
}

// ---------------- gen step: K=512 (Kc=8/lane), 16 o/wave, 2 rows ----------------
// lane -> result: i=(l>>2)&15, b=(l>>1)&1 (dup over l&1)
template<bool FIRST>
__device__ __forceinline__ void gen_step(
    const float* __restrict__ Wj,                    // WgT + j*DMn*DSn
    const float (&lg)[8], const float (&lb)[8], float biasv,
    const float* __restrict__ stj,                   // states[j]
    const int* __restrict__ othf, int target,
    int* __restrict__ myflag, int epoch,
    float& mreg, float& btReg, float eEv,
    float* __restrict__ errj,
    int o, int bg, int grp, int tid, int l, int o0w)
{
  // W first half (8 of 16 o): plain cached loads, issued pre-wait (read-only)
  v4f w0[8][2];
  #pragma unroll
  for (int i = 0; i < 8; i++) {
    const v4f* wp = (const v4f*)(Wj + (size_t)(o0w + i)*DSn + l*8);
    w0[i][0] = wp[0]; w0[i][1] = wp[1];
  }
  waitrole(othf, tid, target);
  // src: both group rows (hazard-carrying, LLC-coherent)
  v4f x0[2], x1[2];
  #pragma unroll
  for (int r = 0; r < 2; r++) {
    const float* sp = stj + (size_t)(grp*2 + r)*DSn + l*8;
    x0[r] = ldx4(sp);
    x1[r] = ldx4(sp + 4);
  }
  asm volatile("s_waitcnt vmcnt(0)" ::: "memory");
  __builtin_amdgcn_sched_barrier(0);
  // LayerNorm, both rows (same per-row order as R8)
  #pragma unroll
  for (int r = 0; r < 2; r++) {
    float s1 = 0.f;
    #pragma unroll
    for (int e = 0; e < 4; e++) { s1 += x0[r][e]; s1 += x1[r][e]; }
    #pragma unroll
    for (int off = 32; off; off >>= 1) s1 += __shfl_xor(s1, off);
    const float mean = s1 * (1.0f/512.0f);
    float s2 = 0.f;
    #pragma unroll
    for (int e = 0; e < 4; e++) {
      float d0 = x0[r][e] - mean; s2 += d0*d0;
      float d1 = x1[r][e] - mean; s2 += d1*d1;
    }
    #pragma unroll
    for (int off = 32; off; off >>= 1) s2 += __shfl_xor(s2, off);
    const float rstd = 1.0f / sqrtf(s2*(1.0f/512.0f) + EPSc);
    #pragma unroll
    for (int e = 0; e < 4; e++) {
      x0[r][e] = (x0[r][e] - mean)*rstd*lg[e]   + lb[e];
      x1[r][e] = (x1[r][e] - mean)*rstd*lg[4+e] + lb[4+e];
    }
  }
  // W second half
  v4f w1[8][2];
  #pragma unroll
  for (int i = 0; i < 8; i++) {
    const v4f* wp = (const v4f*)(Wj + (size_t)(o0w + 8 + i)*DSn + l*8);
    w1[i][0] = wp[0]; w1[i][1] = wp[1];
  }
  // GEMM partials: v[i*2+b] (per-output k-order identical to R8)
  float v[32];
  #pragma unroll
  for (int n = 0; n < 32; n++) v[n] = 0.f;
  #pragma unroll
  for (int b = 0; b < 2; b++)
    #pragma unroll
    for (int i = 0; i < 8; i++) {
      float a = v[i*2 + b];
      #pragma unroll
      for (int e = 0; e < 4; e++) a = fmaf(x0[b][e], w0[i][0][e], a);
      #pragma unroll
      for (int e = 0; e < 4; e++) a = fmaf(x1[b][e], w0[i][1][e], a);
      v[i*2 + b] = a;
    }
  #pragma unroll
  for (int b = 0; b < 2; b++)
    #pragma unroll
    for (int i = 0; i < 8; i++) {
      float a = v[(8+i)*2 + b];
      #pragma unroll
      for (int e = 0; e < 4; e++) a = fmaf(x0[b][e], w1[i][0][e], a);
      #pragma unroll
      for (int e = 0; e < 4; e++) a = fmaf(x1[b][e], w1[i][1][e], a);
      v[(8+i)*2 + b] = a;
    }
  // butterfly reduce-scatter (NV=32), same tree as R8
  bstep<32>(v, (l & 32) != 0, 32);
  bstep<16>(v, (l & 16) != 0, 16);
  bstep<8> (v, (l &  8) != 0,  8);
  bstep<4> (v, (l &  4) != 0,  4);
  bstep<2> (v, (l &  2) != 0,  2);
  v[0] += __shfl_xor(v[0], 1);
  // bias + LIF + err store + publish
  const float val = v[0] + biasv;
  const float mt = mreg * DECAYc + val;
  const float spk = (mt >= THRc) ? 1.f : 0.f;
  mreg = mt * (1.f - spk);
  const float ne = (FIRST ? eEv : btReg) - spk;
  btReg = ne;
  if ((l & 1) == 0) st_cg(errj + (size_t)bg*DMn + o, ne);
  pubrole(myflag, tid, epoch);
}

// ---------------- inf step: K=1024 (Kc=16/lane), 8 o/wave, 2 rows ----------------
// lane -> result: i=(l>>3)&7, b=(l>>2)&1 (dup over l&3)
__device__ __forceinline__ void inf_step(
    const float* __restrict__ Wj,                    // WiT + j*DSn*DMn
    const float (&lg16)[16], const float (&lb16)[16], float biasv,
    const float* __restrict__ errj,
    const int* __restrict__ othf, int target,
    int* __restrict__ myflag, int epoch,
    float& mreg, float& streg, float* __restrict__ stj, float* __restrict__ hsw,
    int o, int bg, int grp, int tid, int l, int o0w)
{
  // W first half (4 of 8 o) pre-wait
  v4f w0[4][4];
  #pragma unroll
  for (int i = 0; i < 4; i++) {
    const v4f* wp = (const v4f*)(Wj + (size_t)(o0w + i)*DMn + l*16);
    #pragma unroll
    for (int q = 0; q < 4; q++) w0[i][q] = wp[q];
  }
  waitrole(othf, tid, target);
  v4f x[2][4];
  #pragma unroll
  for (int r = 0; r < 2; r++) {
    const float* sp = errj + (size_t)(grp*2 + r)*DMn + l*16;
    #pragma unroll
    for (int q = 0; q < 4; q++) x[r][q] = ldx4(sp + 4*q);
  }
  asm volatile("s_waitcnt vmcnt(0)" ::: "memory");
  __builtin_amdgcn_sched_barrier(0);
  // LayerNorm, both rows
  #pragma unroll
  for (int r = 0; r < 2; r++) {
    float s1 = 0.f;
    #pragma unroll
    for (int q = 0; q < 4; q++)
      #pragma unroll
      for (int e = 0; e < 4; e++) s1 += x[r][q][e];
    #pragma unroll
    for (int off = 32; off; off >>= 1) s1 += __shfl_xor(s1, off);
    const float mean = s1 * (1.0f/1024.0f);
    float s2 = 0.f;
    #pragma unroll
    for (int q = 0; q < 4; q++)
      #pragma unroll
      for (int e = 0; e < 4; e++) { float d = x[r][q][e] - mean; s2 += d*d; }
    #pragma unroll
    for (int off = 32; off; off >>= 1) s2 += __shfl_xor(s2, off);
    const float rstd = 1.0f / sqrtf(s2*(1.0f/1024.0f) + EPSc);
    #pragma unroll
    for (int q = 0; q < 4; q++)
      #pragma unroll
      for (int e = 0; e < 4; e++)
        x[r][q][e] = (x[r][q][e] - mean)*rstd*lg16[q*4+e] + lb16[q*4+e];
  }
  // W second half
  v4f w1[4][4];
  #pragma unroll
  for (int i = 0; i < 4; i++) {
    const v4f* wp = (const v4f*)(Wj + (size_t)(o0w + 4 + i)*DMn + l*16);
    #pragma unroll
    for (int q = 0; q < 4; q++) w1[i][q] = wp[q];
  }
  // GEMM partials: v[i*2+b]
  float v[16];
  #pragma unroll
  for (int n = 0; n < 16; n++) v[n] = 0.f;
  #pragma unroll
  for (int b = 0; b < 2; b++)
    #pragma unroll
    for (int i = 0; i < 4; i++) {
      float a = v[i*2 + b];
      #pragma unroll
      for (int q = 0; q < 4; q++)
        #pragma unroll
        for (int e = 0; e < 4; e++) a = fmaf(x[b][q][e], w0[i][q][e], a);
      v[i*2 + b] = a;
    }
  #pragma unroll
  for (int b = 0; b < 2; b++)
    #pragma unroll
    for (int i = 0; i < 4; i++) {
      float a = v[(4+i)*2 + b];
      #pragma unroll
      for (int q = 0; q < 4; q++)
        #pragma unroll
        for (int e = 0; e < 4; e++) a = fmaf(x[b][q][e], w1[i][q][e], a);
      v[(4+i)*2 + b] = a;
    }
  // butterfly reduce-scatter (NV=16), same tree as R8
  bstep<16>(v, (l & 32) != 0, 32);
  bstep<8> (v, (l & 16) != 0, 16);
  bstep<4> (v, (l &  8) != 0,  8);
  bstep<2> (v, (l &  4) != 0,  4);
  v[0] += __shfl_xor(v[0], 2);
  v[0] += __shfl_xor(v[0], 1);
  // bias + LIF + state store + publish
  const float val = v[0] + biasv;
  const float mt = mreg * DECAYc + val;
  const float spk = (mt >= THRc) ? 1.f : 0.f;
  mreg = mt * (1.f - spk);
  const float ns = streg + spk;
  streg = ns;
  if ((l & 3) == 0) {
    st_cg(stj + (size_t)bg*DSn + o, ns);
    if (hsw) hsw[(size_t)bg*DSn + o] = ns;   // plain; consumed post-kernel
  }
  pubrole(myflag, tid, epoch);
}

__global__ void __launch_bounds__(TPB, 1) snn_scan(SP p, char* __restrict__ ws)
{
  extern __shared__ float Xpad[];  // 84 KiB dynamic (R7/R8-proven) -> 1 WG/CU
  (void)Xpad;
  const int bid = blockIdx.x, tid = threadIdx.x;
  const int grp = bid & 7, wgl = bid >> 3;   // static mapping, no getreg
  const int w = tid >> 6, l = tid & 63;
  int* flags  = (int*)(ws + OF_FLAGS);
  int* myflag = flags + (size_t)(grp*32 + wgl) * 256;
  float* st0 = (float*)(ws + OF_STATES);
  float* st1 = st0 + (size_t)Bn*DSn;
  float* e0  = (float*)(ws + OF_E0);
  float* e1  = (float*)(ws + OF_E1);
  const float* encX = (const float*)(ws + OF_ENCX);
  float* hs = (float*)(ws + OF_HS);
  const float* WgT = (const float*)(ws + OF_WGT);
  const float* WiT = (const float*)(ws + OF_WIT);

  if (wgl < 16) {
    // ---------------- generative pipeline ----------------
    const int* othf = flags + (size_t)(grp*32 + 16) * 256;   // inf role flags
    const int o0w = wgl*64 + w*16;
    const int i_l = (l >> 2) & 15, b_l = (l >> 1) & 1;
    const int o = o0w + i_l, bg = grp*2 + b_l;
    const float* WA = WgT;
    const float* WB = WgT + (size_t)DMn*DSn;
    float lgA[8], lbA[8], lgB[8], lbB[8];
    {
      const v4f* g0 = (const v4f*)(p.ln_s_g + l*8);
      const v4f* c0 = (const v4f*)(p.ln_s_b + l*8);
      const v4f* g1 = (const v4f*)(p.ln_s_g + DSn + l*8);
      const v4f* c1 = (const v4f*)(p.ln_s_b + DSn + l*8);
      v4f ga = g0[0], gb = g0[1], ba = c0[0], bb = c0[1];
      v4f gc = g1[0], gd = g1[1], bc = c1[0], bd = c1[1];
      #pragma unroll
      for (int e = 0; e < 4; e++) {
        lgA[e] = ga[e]; lgA[4+e] = gb[e]; lbA[e] = ba[e]; lbA[4+e] = bb[e];
        lgB[e] = gc[e]; lgB[4+e] = gd[e]; lbB[e] = bc[e]; lbB[4+e] = bd[e];
      }
    }
    const float biasA = p.bg[o], biasB = p.bg[DMn + o];
    float encMem = 0.f, btReg = 0.f, genMemA = 0.f, genMemB = 0.f;

    for (int s = 0; s < Sn; s++) {
      const int s8 = s*8;
      // inline encoder LIF (token-static input, plain cached load)
      const float ex = encX[(size_t)s*Bn*DMn + (size_t)bg*DMn + o];
      const float emt = encMem*DECAYc + ex;
      const float esp = (emt >= THRc) ? 1.f : 0.f;
      encMem = emt * (1.f - esp);
      gen_step<true >(WA, lgA, lbA, biasA, st0, othf, s8-1, myflag, s8+1,
                      genMemA, btReg, esp, e0, o, bg, grp, tid, l, o0w);
      gen_step<false>(WB, lgB, lbB, biasB, st1, othf, s8+0, myflag, s8+2,
                      genMemB, btReg, 0.f, e1, o, bg, grp, tid, l, o0w);
      gen_step<false>(WA, lgA, lbA, biasA, st0, othf, s8+1, myflag, s8+3,
                      genMemA, btReg, 0.f, e0, o, bg, grp, tid, l, o0w);
      gen_step<false>(WB, lgB, lbB, biasB, st1, othf, s8+2, myflag, s8+4,
                      genMemB, btReg, 0.f, e1, o, bg, grp, tid, l, o0w);
      gen_step<false>(WA, lgA, lbA, biasA, st0, othf, s8+3, myflag, s8+5,
                      genMemA, btReg, 0.f, e0, o, bg, grp, tid, l, o0w);
      gen_step<false>(WB, lgB, lbB, biasB, st1, othf, s8+4, myflag, s8+6,
                      genMemB, btReg, 0.f, e1, o, bg, grp, tid, l, o0w);
      gen_step<false>(WA, lgA, lbA, biasA, st0, othf, s8+5, myflag, s8+7,
                      genMemA, btReg, 0.f, e0, o, bg, grp, tid, l, o0w);
      gen_step<false>(WB, lgB, lbB, biasB, st1, othf, s8+6, myflag, s8+8,
                      genMemB, btReg, 0.f, e1, o, bg, grp, tid, l, o0w);
    }
  } else {
    // ---------------- inference pipeline ----------------
    const int* othf = flags + (size_t)(grp*32) * 256;        // gen role flags
    const int o0w = (wgl - 16)*32 + w*8;
    const int i_l = (l >> 3) & 7, b_l = (l >> 2) & 1;
    const int o = o0w + i_l, bg = grp*2 + b_l;
    const float* WA = WiT;
    const float* WB = WiT + (size_t)DSn*DMn;
    float lgA[16], lbA[16], lgB[16], lbB[16];
    {
      const v4f* g0 = (const v4f*)(p.ln_e_g + l*16);
      const v4f* c0 = (const v4f*)(p.ln_e_b + l*16);
      const v4f* g1 = (const v4f*)(p.ln_e_g + DMn + l*16);
      const v4f* c1 = (const v4f*)(p.ln_e_b + DMn + l*16);
      #pragma unroll
      for (int q = 0; q < 4; q++) {
        v4f ga = g0[q], ba = c0[q], gb = g1[q], bb = c1[q];
        #pragma unroll
        for (int e = 0; e < 4; e++) {
          lgA[q*4+e] = ga[e]; lbA[q*4+e] = ba[e];
          lgB[q*4+e] = gb[e]; lbB[q*4+e] = bb[e];
        }
      }
    }
    const float biasA = p.bi[o], biasB = p.bi[DSn + o];
    float infMemA = 0.f, infMemB = 0.f, stRegA = 0.f, stRegB = 0.f;

    for (int s = 0; s < Sn; s++) {
      const int s8 = s*8;
      inf_step(WA, lgA, lbA, biasA, e0, othf, s8+1, myflag, s8+1,
               infMemA, stRegA, st0, nullptr, o, bg, grp, tid, l, o0w);
      inf_step(WB, lgB, lbB, biasB, e1, othf, s8+2, myflag, s8+2,
               infMemB, stRegB, st1, nullptr, o, bg, grp, tid, l, o0w);
      inf_step(WA, lgA, lbA, biasA, e0, othf, s8+3, myflag, s8+3,
               infMemA, stRegA, st0, nullptr, o, bg, grp, tid, l, o0w);
      inf_step(WB, lgB, lbB, biasB, e1, othf, s8+4, myflag, s8+4,
               infMemB, stRegB, st1, nullptr, o, bg, grp, tid, l, o0w);
      inf_step(WA, lgA, lbA, biasA, e0, othf, s8+5, myflag, s8+5,
               infMemA, stRegA, st0, nullptr, o, bg, grp, tid, l, o0w);
      inf_step(WB, lgB, lbB, biasB, e1, othf, s8+6, myflag, s8+6,
               infMemB, stRegB, st1, nullptr, o, bg, grp, tid, l, o0w);
      inf_step(WA, lgA, lbA, biasA, e0, othf, s8+7, myflag, s8+7,
               infMemA, stRegA, st0, nullptr, o, bg, grp, tid, l, o0w);
      inf_step(WB, lgB, lbB, biasB, e1, othf, s8+8, myflag, s8+8,
               infMemB, stRegB, st1, hs + (size_t)s*Bn*DSn, o, bg, grp, tid, l, o0w);
    }
  }
}

// tiled transpose: in [K][O] -> out [O][K]
__global__ void __launch_bounds__(256) transpose_k(
    const float* __restrict__ in, float* __restrict__ out, int K, int O)
{
  __shared__ float t[32][33];
  const int ob = blockIdx.x * 32, kb = blockIdx.y * 32;
  const int x = threadIdx.x, y = threadIdx.y;
  #pragma unroll
  for (int i = 0; i < 32; i += 8) t[y + i][x] = in[(size_t)(kb + y + i)*O + ob + x];
  __syncthreads();
  #pragma unroll
  for (int i = 0; i < 32; i += 8) out[(size_t)(ob + y + i)*K + kb + x] = t[x][y + i];
}

// encX = gather(emb, ids) @ W_enc + b_enc   (M=2048, K=1024, N=1024) — raw, no LIF
__global__ void __launch_bounds__(256) enc_gemm(
    const int* __restrict__ ids, const float* __restrict__ emb,
    const float* __restrict__ We, const float* __restrict__ be,
    float* __restrict__ encX)
{
  __shared__ float As[32][128];
  __shared__ float Bs[32][128];
  __shared__ int rowid[128];
  const int tid = threadIdx.x;
  const int ntile = blockIdx.x * 128;
  const int mtile = blockIdx.y * 128;
  if (tid < 128) {
    int m = mtile + tid;                  // m = s*16 + b
    rowid[tid] = ids[(m & 15)*Sn + (m >> 4)];
  }
  __syncthreads();
  const int tx = tid & 15, ty = tid >> 4;
  float acc[8][8];
  #pragma unroll
  for (int i = 0; i < 8; i++)
    #pragma unroll
    for (int q = 0; q < 8; q++) acc[i][q] = 0.f;

  for (int kb = 0; kb < 32; kb++) {
    #pragma unroll
    for (int r = 0; r < 4; r++) {
      int idx = tid + r*256;
      int m = idx >> 3, kq = idx & 7;
      float4 a = *(const float4*)(emb + (size_t)rowid[m]*DMn + kb*32 + kq*4);
      As[kq*4+0][m] = a.x; As[kq*4+1][m] = a.y;
      As[kq*4+2][m] = a.z; As[kq*4+3][m] = a.w;
    }
    #pragma unroll
    for (int r = 0; r < 4; r++) {
      int idx = tid + r*256;
      int k = idx >> 5, nq = idx & 31;
      *(float4*)(&Bs[k][nq*4]) =
          *(const float4*)(We + (size_t)(kb*32 + k)*DMn + ntile + nq*4);
    }
    __syncthreads();
    #pragma unroll
    for (int k = 0; k < 32; k++) {
      float4 a0 = *(float4*)(&As[k][ty*8]);
      float4 a1 = *(float4*)(&As[k][ty*8+4]);
      float4 b0 = *(float4*)(&Bs[k][tx*8]);
      float4 b1 = *(float4*)(&Bs[k][tx*8+4]);
      float av[8] = {a0.x,a0.y,a0.z,a0.w,a1.x,a1.y,a1.z,a1.w};
      float bv[8] = {b0.x,b0.y,b0.z,b0.w,b1.x,b1.y,b1.z,b1.w};
      #pragma unroll
      for (int i = 0; i < 8; i++)
        #pragma unroll
        for (int q = 0; q < 8; q++) acc[i][q] += av[i]*bv[q];
    }
    __syncthreads();
  }
  const float* bop = be + ntile + tx*8;
  float4 bv0 = *(const float4*)bop;
  float4 bv1 = *(const float4*)(bop + 4);
  #pragma unroll
  for (int i = 0; i < 8; i++) {
    int m = mtile + ty*8 + i;
    float* op = encX + (size_t)m*DMn + ntile + tx*8;
    float4 v0 = make_float4(acc[i][0]+bv0.x, acc[i][1]+bv0.y,
                            acc[i][2]+bv0.z, acc[i][3]+bv0.w);
    float4 v1 = make_float4(acc[i][4]+bv1.x, acc[i][5]+bv1.y,
                            acc[i][6]+bv1.z, acc[i][7]+bv1.w);
    *(float4*)op = v0;
    *(float4*)(op + 4) = v1;
  }
}

// logits = hs @ W_out + b_out, fp32, 128x128 tile, 8x8 microtile
__global__ void __launch_bounds__(256) out_gemm(
    const float* __restrict__ hs, const float* __restrict__ Wo,
    const float* __restrict__ bo, float* __restrict__ out)
{
  __shared__ float As[32][128];
  __shared__ float Bs[32][128];
  const int tid = threadIdx.x;
  const int ntile = blockIdx.x * 128;
  const int mtile = blockIdx.y * 128;
  const int tx = tid & 15, ty = tid >> 4;
  float acc[8][8];
  #pragma unroll
  for (int i = 0; i < 8; i++)
    #pragma unroll
    for (int q = 0; q < 8; q++) acc[i][q] = 0.f;

  for (int kb = 0; kb < 16; kb++) {
    #pragma unroll
    for (int r = 0; r < 4; r++) {
      int idx = tid + r*256;
      int m = idx >> 3, kq = idx & 7;
      float4 a = *(const float4*)(hs + (size_t)(mtile + m)*512 + kb*32 + kq*4);
      As[kq*4+0][m] = a.x; As[kq*4+1][m] = a.y;
      As[kq*4+2][m] = a.z; As[kq*4+3][m] = a.w;
    }
    #pragma unroll
    for (int r = 0; r < 4; r++) {
      int idx = tid + r*256;
      int k = idx >> 5, nq = idx & 31;
      *(float4*)(&Bs[k][nq*4]) =
          *(const float4*)(Wo + (size_t)(kb*32 + k)*Vn + ntile + nq*4);
    }
    __syncthreads();
    #pragma unroll
    for (int k = 0; k < 32; k++) {
      float4 a0 = *(float4*)(&As[k][ty*8]);
      float4 a1 = *(float4*)(&As[k][ty*8+4]);
      float4 b0 = *(float4*)(&Bs[k][tx*8]);
      float4 b1 = *(float4*)(&Bs[k][tx*8+4]);
      float av[8] = {a0.x,a0.y,a0.z,a0.w,a1.x,a1.y,a1.z,a1.w};
      float bv[8] = {b0.x,b0.y,b0.z,b0.w,b1.x,b1.y,b1.z,b1.w};
      #pragma unroll
      for (int i = 0; i < 8; i++)
        #pragma unroll
        for (int q = 0; q < 8; q++) acc[i][q] += av[i]*bv[q];
    }
    __syncthreads();
  }
  const float* bop = bo + ntile + tx*8;
  float4 bv0 = *(const float4*)bop;
  float4 bv1 = *(const float4*)(bop + 4);
  #pragma unroll
  for (int i = 0; i < 8; i++) {
    int m = mtile + ty*8 + i;            // m = s*16 + b
    float* op = out + ((size_t)(m & 15)*Sn + (m >> 4))*Vn + ntile + tx*8;
    float4 v0 = make_float4(acc[i][0]+bv0.x, acc[i][1]+bv0.y,
                            acc[i][2]+bv0.z, acc[i][3]+bv0.w);
    float4 v1 = make_float4(acc[i][4]+bv1.x, acc[i][5]+bv1.y,
                            acc[i][6]+bv1.z, acc[i][7]+bv1.w);
    *(float4*)op = v0;
    *(float4*)(op + 4) = v1;
  }
}

extern "C" void kernel_launch(void* const* d_in, const int* in_sizes, int n_in,
                              void* d_out, int out_size, void* d_ws, size_t ws_size,
                              hipStream_t stream) {
  (void)in_sizes; (void)n_in; (void)out_size; (void)ws_size;
  SP p;
  p.ids    = (const int*)  d_in[0];
  p.emb    = (const float*)d_in[1];
  p.W_enc  = (const float*)d_in[2];
  p.b_enc  = (const float*)d_in[3];
  p.ln_s_g = (const float*)d_in[4];
  p.ln_s_b = (const float*)d_in[5];
  p.Wg     = (const float*)d_in[6];
  p.bg     = (const float*)d_in[7];
  p.ln_e_g = (const float*)d_in[8];
  p.ln_e_b = (const float*)d_in[9];
  p.Wi     = (const float*)d_in[10];
  p.bi     = (const float*)d_in[11];
  const float* Wo = (const float*)d_in[12];
  const float* bo = (const float*)d_in[13];

  char* ws = (char*)d_ws;
  float* WgT  = (float*)(ws + OF_WGT);
  float* WiT  = (float*)(ws + OF_WIT);
  float* encX = (float*)(ws + OF_ENCX);
  float* hs   = (float*)(ws + OF_HS);

  hipMemsetAsync(ws, 0, INIT_BYTES, stream);   // flags + states = 0

  hipLaunchKernelGGL(transpose_k, dim3(32, 16), dim3(32, 8), 0, stream,
                     p.Wg, WgT, 512, 1024);
  hipLaunchKernelGGL(transpose_k, dim3(32, 16), dim3(32, 8), 0, stream,
                     p.Wg + (size_t)512*1024, WgT + (size_t)1024*512, 512, 1024);
  hipLaunchKernelGGL(transpose_k, dim3(16, 32), dim3(32, 8), 0, stream,
                     p.Wi, WiT, 1024, 512);
  hipLaunchKernelGGL(transpose_k, dim3(16, 32), dim3(32, 8), 0, stream,
                     p.Wi + (size_t)1024*512, WiT + (size_t)512*1024, 1024, 512);

  hipLaunchKernelGGL(enc_gemm, dim3(DMn/128, 2048/128), dim3(256), 0, stream,
                     p.ids, p.emb, p.W_enc, p.b_enc, encX);

  hipLaunchKernelGGL(snn_scan, dim3(NWG), dim3(TPB), 86016, stream, p, ws);

  hipLaunchKernelGGL(out_gemm, dim3(Vn/128, 2048/128), dim3(256), 0, stream,
                     hs, Wo, bo, (float*)d_out);
}

// Round 14
// 4511.171 us; speedup vs baseline: 1.9225x; 1.4283x over previous
//
#include <hip/hip_runtime.h>
#include <math.h>

#define NWG 256
#define TPB 256

typedef float v4f __attribute__((ext_vector_type(4)));

constexpr int Bn = 16, Sn = 128, Vn = 32000, DMn = 1024, DSn = 512;
constexpr float DECAYc = 0.6065306597126334f;  // exp(-1/tau), tau=2
constexpr float THRc = 1.0f, EPSc = 1e-5f;

// ---- workspace byte offsets (R12 layout) ----
constexpr size_t OF_FLAGS  = 0;                                   // 256 role-flags * 1KB
constexpr size_t OF_STATES = (size_t)256*4096;                    // [2][16][512]
constexpr size_t OF_E0     = OF_STATES + (size_t)2*16*512*4;      // [16][1024]
constexpr size_t OF_E1     = OF_E0 + (size_t)16*1024*4;
constexpr size_t OF_ENCX   = OF_E1 + (size_t)16*1024*4;           // [128][16][1024] raw enc GEMM
constexpr size_t OF_HS     = OF_ENCX + (size_t)128*16*1024*4;     // [128][16][512]
constexpr size_t OF_WGT    = OF_HS + (size_t)128*16*512*4;        // WgT [2][1024][512]
constexpr size_t OF_WIT    = OF_WGT + (size_t)2*1024*512*4;       // WiT [2][512][1024]
constexpr size_t INIT_BYTES = OF_E0;   // zero flags + states

struct SP {
  const int* ids; const float* emb;
  const float* W_enc; const float* b_enc;
  const float* ln_s_g; const float* ln_s_b;
  const float* Wg; const float* bg;
  const float* ln_e_g; const float* ln_e_b;
  const float* Wi; const float* bi;
};

// Proven primitives (R5-R8/R12): LLC-coherent via __hip_atomic relaxed agent /
// sc0 sc1 asm loads. No fences anywhere. No other memory semantics used.
__device__ __forceinline__ void st_cg(float* p, float v) {
  __hip_atomic_store(p, v, __ATOMIC_RELAXED, __HIP_MEMORY_SCOPE_AGENT);
}
__device__ __forceinline__ int ld_flag(const int* p) {
  return __hip_atomic_load(p, __ATOMIC_RELAXED, __HIP_MEMORY_SCOPE_AGENT);
}
__device__ __forceinline__ void st_flag(int* p, int v) {
  __hip_atomic_store(p, v, __ATOMIC_RELAXED, __HIP_MEMORY_SCOPE_AGENT);
}
__device__ __forceinline__ v4f ldx4(const float* p) {
  v4f r;
  asm volatile("global_load_dwordx4 %0, %1, off sc0 sc1" : "=v"(r) : "v"(p));
  return r;
}

// 16B-chunk XOR swizzle (involution; proven R3-R5) — kills the stride-8
// bank pattern of per-lane W reads from LDS.
__device__ __forceinline__ int swc2(int c) { return c ^ ((c >> 3) & 7); }

// one butterfly reduce-scatter step: SZ live values -> SZ/2, partner lane ^M.
template<int SZ>
__device__ __forceinline__ void bstep(float* v, bool up, int M) {
  #pragma unroll
  for (int q = 0; q < SZ/2; q++) {
    float lo = v[q], hi = v[q + SZ/2];
    float send = up ? lo : hi;
    float recv = __shfl_xor(send, M);
    v[q] = (up ? hi : lo) + recv;
  }
}

// wait: lanes 0..15 poll the 16 producer-role flags, then gate the WG (R12).
__device__ __forceinline__ void waitrole(const int* base, int tid, int target) {
  if (tid < 16) {
    const int* p = base + (size_t)tid * 256;
    while (ld_flag(p) < target) { }
  }
  asm volatile("" ::: "memory");
  __syncthreads();
}
// publish: each wave drains its stores, WG barrier, tid0 stores epoch (R12).
__device__ __forceinline__ void pubrole(int* myflag, int tid, int epoch) {
  asm volatile("s_waitcnt vmcnt(0)" ::: "memory");
  __syncthreads();
  if (tid == 0) st_flag(myflag, epoch);
}

// ---------------- gen step: K=512 (Kc=8/lane), 16 o/wave, 2 rows ----------------
// BLDS=false: W from persistent regs (matrix A). BLDS=true: W read from LDS
// (matrix B, staged+swizzled at startup). lane -> i=(l>>2)&15, b=(l>>1)&1.
template<bool FIRST, bool BLDS>
__device__ __forceinline__ void gen_step(
    const v4f (&wv)[16][2], const v4f* __restrict__ wl, int o0l,
    const float (&lg)[8], const float (&lb)[8], float biasv,
    const float* __restrict__ stj,                   // states[j]
    const int* __restrict__ othf, int target,
    int* __restrict__ myflag, int epoch,
    float& mreg, float& btReg, float eEv,
    float* __restrict__ errj,
    int o, int bg, int grp, int tid, int l)
{
  // ---- W for this step (LDS reads are static data; issue before the wait) ----
  v4f wt[16][2];
  if constexpr (BLDS) {
    #pragma unroll
    for (int i = 0; i < 16; i++) {
      wt[i][0] = wl[(o0l + i)*128 + swc2(2*l + 0)];
      wt[i][1] = wl[(o0l + i)*128 + swc2(2*l + 1)];
    }
  }
  waitrole(othf, tid, target);
  // src: both group rows (hazard-carrying, LLC-coherent)
  v4f x0[2], x1[2];
  #pragma unroll
  for (int r = 0; r < 2; r++) {
    const float* sp = stj + (size_t)(grp*2 + r)*DSn + l*8;
    x0[r] = ldx4(sp);
    x1[r] = ldx4(sp + 4);
  }
  asm volatile("s_waitcnt vmcnt(0)" ::: "memory");
  __builtin_amdgcn_sched_barrier(0);
  // LayerNorm, both rows (same order as R12)
  #pragma unroll
  for (int r = 0; r < 2; r++) {
    float s1 = 0.f;
    #pragma unroll
    for (int e = 0; e < 4; e++) { s1 += x0[r][e]; s1 += x1[r][e]; }
    #pragma unroll
    for (int off = 32; off; off >>= 1) s1 += __shfl_xor(s1, off);
    const float mean = s1 * (1.0f/512.0f);
    float s2 = 0.f;
    #pragma unroll
    for (int e = 0; e < 4; e++) {
      float d0 = x0[r][e] - mean; s2 += d0*d0;
      float d1 = x1[r][e] - mean; s2 += d1*d1;
    }
    #pragma unroll
    for (int off = 32; off; off >>= 1) s2 += __shfl_xor(s2, off);
    const float rstd = 1.0f / sqrtf(s2*(1.0f/512.0f) + EPSc);
    #pragma unroll
    for (int e = 0; e < 4; e++) {
      x0[r][e] = (x0[r][e] - mean)*rstd*lg[e]   + lb[e];
      x1[r][e] = (x1[r][e] - mean)*rstd*lg[4+e] + lb[4+e];
    }
  }
  // GEMM partials: v[i*2+b] (per-output k-order identical to R12)
  float v[32];
  #pragma unroll
  for (int n = 0; n < 32; n++) v[n] = 0.f;
  #pragma unroll
  for (int b = 0; b < 2; b++)
    #pragma unroll
    for (int i = 0; i < 16; i++) {
      float a = v[i*2 + b];
      #pragma unroll
      for (int e = 0; e < 4; e++)
        a = fmaf(x0[b][e], (BLDS ? wt[i][0][e] : wv[i][0][e]), a);
      #pragma unroll
      for (int e = 0; e < 4; e++)
        a = fmaf(x1[b][e], (BLDS ? wt[i][1][e] : wv[i][1][e]), a);
      v[i*2 + b] = a;
    }
  // butterfly reduce-scatter (NV=32), same tree as R12
  bstep<32>(v, (l & 32) != 0, 32);
  bstep<16>(v, (l & 16) != 0, 16);
  bstep<8> (v, (l &  8) != 0,  8);
  bstep<4> (v, (l &  4) != 0,  4);
  bstep<2> (v, (l &  2) != 0,  2);
  v[0] += __shfl_xor(v[0], 1);
  // bias + LIF + err store + publish
  const float val = v[0] + biasv;
  const float mt = mreg * DECAYc + val;
  const float spk = (mt >= THRc) ? 1.f : 0.f;
  mreg = mt * (1.f - spk);
  const float ne = (FIRST ? eEv : btReg) - spk;
  btReg = ne;
  if ((l & 1) == 0) st_cg(errj + (size_t)bg*DMn + o, ne);
  pubrole(myflag, tid, epoch);
}

// ---------------- inf step: K=1024 (Kc=16/lane), 8 o/wave, 2 rows ----------------
// lane -> i=(l>>3)&7, b=(l>>2)&1.
template<bool BLDS>
__device__ __forceinline__ void inf_step(
    const v4f (&wv)[8][4], const v4f* __restrict__ wl, int o0l,
    const float (&lg16)[16], const float (&lb16)[16], float biasv,
    const float* __restrict__ errj,
    const int* __restrict__ othf, int target,
    int* __restrict__ myflag, int epoch,
    float& mreg, float& streg, float* __restrict__ stj, float* __restrict__ hsw,
    int o, int bg, int grp, int tid, int l)
{
  v4f wt[8][4];
  if constexpr (BLDS) {
    #pragma unroll
    for (int i = 0; i < 8; i++)
      #pragma unroll
      for (int q = 0; q < 4; q++)
        wt[i][q] = wl[(o0l + i)*256 + swc2(4*l + q)];
  }
  waitrole(othf, tid, target);
  v4f x[2][4];
  #pragma unroll
  for (int r = 0; r < 2; r++) {
    const float* sp = errj + (size_t)(grp*2 + r)*DMn + l*16;
    #pragma unroll
    for (int q = 0; q < 4; q++) x[r][q] = ldx4(sp + 4*q);
  }
  asm volatile("s_waitcnt vmcnt(0)" ::: "memory");
  __builtin_amdgcn_sched_barrier(0);
  // LayerNorm, both rows (same order as R12)
  #pragma unroll
  for (int r = 0; r < 2; r++) {
    float s1 = 0.f;
    #pragma unroll
    for (int q = 0; q < 4; q++)
      #pragma unroll
      for (int e = 0; e < 4; e++) s1 += x[r][q][e];
    #pragma unroll
    for (int off = 32; off; off >>= 1) s1 += __shfl_xor(s1, off);
    const float mean = s1 * (1.0f/1024.0f);
    float s2 = 0.f;
    #pragma unroll
    for (int q = 0; q < 4; q++)
      #pragma unroll
      for (int e = 0; e < 4; e++) { float d = x[r][q][e] - mean; s2 += d*d; }
    #pragma unroll
    for (int off = 32; off; off >>= 1) s2 += __shfl_xor(s2, off);
    const float rstd = 1.0f / sqrtf(s2*(1.0f/1024.0f) + EPSc);
    #pragma unroll
    for (int q = 0; q < 4; q++)
      #pragma unroll
      for (int e = 0; e < 4; e++)
        x[r][q][e] = (x[r][q][e] - mean)*rstd*lg16[q*4+e] + lb16[q*4+e];
  }
  // GEMM partials: v[i*2+b]
  float v[16];
  #pragma unroll
  for (int n = 0; n < 16; n++) v[n] = 0.f;
  #pragma unroll
  for (int b = 0; b < 2; b++)
    #pragma unroll
    for (int i = 0; i < 8; i++) {
      float a = v[i*2 + b];
      #pragma unroll
      for (int q = 0; q < 4; q++)
        #pragma unroll
        for (int e = 0; e < 4; e++)
          a = fmaf(x[b][q][e], (BLDS ? wt[i][q][e] : wv[i][q][e]), a);
      v[i*2 + b] = a;
    }
  // butterfly reduce-scatter (NV=16), same tree as R12
  bstep<16>(v, (l & 32) != 0, 32);
  bstep<8> (v, (l & 16) != 0, 16);
  bstep<4> (v, (l &  8) != 0,  8);
  bstep<2> (v, (l &  4) != 0,  4);
  v[0] += __shfl_xor(v[0], 2);
  v[0] += __shfl_xor(v[0], 1);
  // bias + LIF + state store + publish
  const float val = v[0] + biasv;
  const float mt = mreg * DECAYc + val;
  const float spk = (mt >= THRc) ? 1.f : 0.f;
  mreg = mt * (1.f - spk);
  const float ns = streg + spk;
  streg = ns;
  if ((l & 3) == 0) {
    st_cg(stj + (size_t)bg*DSn + o, ns);
    if (hsw) hsw[(size_t)bg*DSn + o] = ns;   // plain; flushed at kernel end
  }
  pubrole(myflag, tid, epoch);
}

__global__ void __launch_bounds__(TPB, 1) snn_scan(SP p, char* __restrict__ ws)
{
  extern __shared__ float Xpad[];  // 128 KiB dynamic: B-matrix slice + 1 WG/CU pin
  const int bid = blockIdx.x, tid = threadIdx.x;
  const int grp = bid & 7, wgl = bid >> 3;   // static mapping (R12-proven)
  const int w = tid >> 6, l = tid & 63;
  int* flags  = (int*)(ws + OF_FLAGS);
  int* myflag = flags + (size_t)(grp*32 + wgl) * 256;
  float* st0 = (float*)(ws + OF_STATES);
  float* st1 = st0 + (size_t)Bn*DSn;
  float* e0  = (float*)(ws + OF_E0);
  float* e1  = (float*)(ws + OF_E1);
  const float* encX = (const float*)(ws + OF_ENCX);
  float* hs = (float*)(ws + OF_HS);
  const float* WgT = (const float*)(ws + OF_WGT);
  const float* WiT = (const float*)(ws + OF_WIT);
  const v4f* wl = (const v4f*)Xpad;

  if (wgl < 16) {
    // ---------------- generative pipeline ----------------
    const int* othf = flags + (size_t)(grp*32 + 16) * 256;   // inf role flags
    const int o0w = wgl*64 + w*16;
    const int i_l = (l >> 2) & 15, b_l = (l >> 1) & 1;
    const int o = o0w + i_l, bg = grp*2 + b_l;
    // ---- stage matrix B (j=1) rows [wgl*64 .. +64) into LDS, swizzled ----
    {
      const float* WB = WgT + (size_t)DMn*DSn + (size_t)(wgl*64)*DSn;
      v4f* dst = (v4f*)Xpad;
      for (int cc = tid; cc < 64*128; cc += TPB) {
        const int row = cc >> 7, c = cc & 127;
        dst[row*128 + swc2(c)] = *(const v4f*)(WB + (size_t)row*DSn + c*4);
      }
    }
    // ---- matrix A (j=0) persistent in registers (128 VGPR, R8-proven size) ----
    v4f wA[16][2];
    #pragma unroll
    for (int i = 0; i < 16; i++) {
      const v4f* pa = (const v4f*)(WgT + (size_t)(o0w + i)*DSn + l*8);
      wA[i][0] = pa[0]; wA[i][1] = pa[1];
    }
    float lgA[8], lbA[8], lgB[8], lbB[8];
    {
      const v4f* g0 = (const v4f*)(p.ln_s_g + l*8);
      const v4f* c0 = (const v4f*)(p.ln_s_b + l*8);
      const v4f* g1 = (const v4f*)(p.ln_s_g + DSn + l*8);
      const v4f* c1 = (const v4f*)(p.ln_s_b + DSn + l*8);
      v4f ga = g0[0], gb = g0[1], ba = c0[0], bb = c0[1];
      v4f gc = g1[0], gd = g1[1], bc = c1[0], bd = c1[1];
      #pragma unroll
      for (int e = 0; e < 4; e++) {
        lgA[e] = ga[e]; lgA[4+e] = gb[e]; lbA[e] = ba[e]; lbA[4+e] = bb[e];
        lgB[e] = gc[e]; lgB[4+e] = gd[e]; lbB[e] = bc[e]; lbB[4+e] = bd[e];
      }
    }
    const float biasA = p.bg[o], biasB = p.bg[DMn + o];
    float encMem = 0.f, btReg = 0.f, genMemA = 0.f, genMemB = 0.f;
    const int o0l = w*16;        // local LDS row base for this wave
    __syncthreads();             // B staged

    for (int s = 0; s < Sn; s++) {
      const int s8 = s*8;
      // inline encoder LIF (token-static input, plain cached load)
      const float ex = encX[(size_t)s*Bn*DMn + (size_t)bg*DMn + o];
      const float emt = encMem*DECAYc + ex;
      const float esp = (emt >= THRc) ? 1.f : 0.f;
      encMem = emt * (1.f - esp);
      gen_step<true ,false>(wA, wl, o0l, lgA, lbA, biasA, st0, othf, s8-1, myflag, s8+1,
                            genMemA, btReg, esp, e0, o, bg, grp, tid, l);
      gen_step<false,true >(wA, wl, o0l, lgB, lbB, biasB, st1, othf, s8+0, myflag, s8+2,
                            genMemB, btReg, 0.f, e1, o, bg, grp, tid, l);
      gen_step<false,false>(wA, wl, o0l, lgA, lbA, biasA, st0, othf, s8+1, myflag, s8+3,
                            genMemA, btReg, 0.f, e0, o, bg, grp, tid, l);
      gen_step<false,true >(wA, wl, o0l, lgB, lbB, biasB, st1, othf, s8+2, myflag, s8+4,
                            genMemB, btReg, 0.f, e1, o, bg, grp, tid, l);
      gen_step<false,false>(wA, wl, o0l, lgA, lbA, biasA, st0, othf, s8+3, myflag, s8+5,
                            genMemA, btReg, 0.f, e0, o, bg, grp, tid, l);
      gen_step<false,true >(wA, wl, o0l, lgB, lbB, biasB, st1, othf, s8+4, myflag, s8+6,
                            genMemB, btReg, 0.f, e1, o, bg, grp, tid, l);
      gen_step<false,false>(wA, wl, o0l, lgA, lbA, biasA, st0, othf, s8+5, myflag, s8+7,
                            genMemA, btReg, 0.f, e0, o, bg, grp, tid, l);
      gen_step<false,true >(wA, wl, o0l, lgB, lbB, biasB, st1, othf, s8+6, myflag, s8+8,
                            genMemB, btReg, 0.f, e1, o, bg, grp, tid, l);
    }
  } else {
    // ---------------- inference pipeline ----------------
    const int* othf = flags + (size_t)(grp*32) * 256;        // gen role flags
    const int o0w = (wgl - 16)*32 + w*8;
    const int i_l = (l >> 3) & 7, b_l = (l >> 2) & 1;
    const int o = o0w + i_l, bg = grp*2 + b_l;
    // ---- stage matrix B (j=1) rows [(wgl-16)*32 .. +32) into LDS, swizzled ----
    {
      const float* WB = WiT + (size_t)DSn*DMn + (size_t)((wgl-16)*32)*DMn;
      v4f* dst = (v4f*)Xpad;
      for (int cc = tid; cc < 32*256; cc += TPB) {
        const int row = cc >> 8, c = cc & 255;
        dst[row*256 + swc2(c)] = *(const v4f*)(WB + (size_t)row*DMn + c*4);
      }
    }
    // ---- matrix A persistent in registers (128 VGPR) ----
    v4f wA[8][4];
    #pragma unroll
    for (int i = 0; i < 8; i++) {
      const v4f* pa = (const v4f*)(WiT + (size_t)(o0w + i)*DMn + l*16);
      #pragma unroll
      for (int q = 0; q < 4; q++) wA[i][q] = pa[q];
    }
    float lgA[16], lbA[16], lgB[16], lbB[16];
    {
      const v4f* g0 = (const v4f*)(p.ln_e_g + l*16);
      const v4f* c0 = (const v4f*)(p.ln_e_b + l*16);
      const v4f* g1 = (const v4f*)(p.ln_e_g + DMn + l*16);
      const v4f* c1 = (const v4f*)(p.ln_e_b + DMn + l*16);
      #pragma unroll
      for (int q = 0; q < 4; q++) {
        v4f ga = g0[q], ba = c0[q], gb = g1[q], bb = c1[q];
        #pragma unroll
        for (int e = 0; e < 4; e++) {
          lgA[q*4+e] = ga[e]; lbA[q*4+e] = ba[e];
          lgB[q*4+e] = gb[e]; lbB[q*4+e] = bb[e];
        }
      }
    }
    const float biasA = p.bi[o], biasB = p.bi[DSn + o];
    float infMemA = 0.f, infMemB = 0.f, stRegA = 0.f, stRegB = 0.f;
    const int o0l = w*8;
    __syncthreads();             // B staged

    for (int s = 0; s < Sn; s++) {
      const int s8 = s*8;
      inf_step<false>(wA, wl, o0l, lgA, lbA, biasA, e0, othf, s8+1, myflag, s8+1,
                      infMemA, stRegA, st0, nullptr, o, bg, grp, tid, l);
      inf_step<true >(wA, wl, o0l, lgB, lbB, biasB, e1, othf, s8+2, myflag, s8+2,
                      infMemB, stRegB, st1, nullptr, o, bg, grp, tid, l);
      inf_step<false>(wA, wl, o0l, lgA, lbA, biasA, e0, othf, s8+3, myflag, s8+3,
                      infMemA, stRegA, st0, nullptr, o, bg, grp, tid, l);
      inf_step<true >(wA, wl, o0l, lgB, lbB, biasB, e1, othf, s8+4, myflag, s8+4,
                      infMemB, stRegB, st1, nullptr, o, bg, grp, tid, l);
      inf_step<false>(wA, wl, o0l, lgA, lbA, biasA, e0, othf, s8+5, myflag, s8+5,
                      infMemA, stRegA, st0, nullptr, o, bg, grp, tid, l);
      inf_step<true >(wA, wl, o0l, lgB, lbB, biasB, e1, othf, s8+6, myflag, s8+6,
                      infMemB, stRegB, st1, nullptr, o, bg, grp, tid, l);
      inf_step<false>(wA, wl, o0l, lgA, lbA, biasA, e0, othf, s8+7, myflag, s8+7,
                      infMemA, stRegA, st0, nullptr, o, bg, grp, tid, l);
      inf_step<true >(wA, wl, o0l, lgB, lbB, biasB, e1, othf, s8+8, myflag, s8+8,
                      infMemB, stRegB, st1, hs + (size_t)s*Bn*DSn, o, bg, grp, tid, l);
    }
  }
}

// tiled transpose: in [K][O] -> out [O][K]
__global__ void __launch_bounds__(256) transpose_k(
    const float* __restrict__ in, float* __restrict__ out, int K, int O)
{
  __shared__ float t[32][33];
  const int ob = blockIdx.x * 32, kb = blockIdx.y * 32;
  const int x = threadIdx.x, y = threadIdx.y;
  #pragma unroll
  for (int i = 0; i < 32; i += 8) t[y + i][x] = in[(size_t)(kb + y + i)*O + ob + x];
  __syncthreads();
  #pragma unroll
  for (int i = 0; i < 32; i += 8) out[(size_t)(ob + y + i)*K + kb + x] = t[x][y + i];
}

// encX = gather(emb, ids) @ W_enc + b_enc   (M=2048, K=1024, N=1024) — raw, no LIF
__global__ void __launch_bounds__(256) enc_gemm(
    const int* __restrict__ ids, const float* __restrict__ emb,
    const float* __restrict__ We, const float* __restrict__ be,
    float* __restrict__ encX)
{
  __shared__ float As[32][128];
  __shared__ float Bs[32][128];
  __shared__ int rowid[128];
  const int tid = threadIdx.x;
  const int ntile = blockIdx.x * 128;
  const int mtile = blockIdx.y * 128;
  if (tid < 128) {
    int m = mtile + tid;                  // m = s*16 + b
    rowid[tid] = ids[(m & 15)*Sn + (m >> 4)];
  }
  __syncthreads();
  const int tx = tid & 15, ty = tid >> 4;
  float acc[8][8];
  #pragma unroll
  for (int i = 0; i < 8; i++)
    #pragma unroll
    for (int q = 0; q < 8; q++) acc[i][q] = 0.f;

  for (int kb = 0; kb < 32; kb++) {
    #pragma unroll
    for (int r = 0; r < 4; r++) {
      int idx = tid + r*256;
      int m = idx >> 3, kq = idx & 7;
      float4 a = *(const float4*)(emb + (size_t)rowid[m]*DMn + kb*32 + kq*4);
      As[kq*4+0][m] = a.x; As[kq*4+1][m] = a.y;
      As[kq*4+2][m] = a.z; As[kq*4+3][m] = a.w;
    }
    #pragma unroll
    for (int r = 0; r < 4; r++) {
      int idx = tid + r*256;
      int k = idx >> 5, nq = idx & 31;
      *(float4*)(&Bs[k][nq*4]) =
          *(const float4*)(We + (size_t)(kb*32 + k)*DMn + ntile + nq*4);
    }
    __syncthreads();
    #pragma unroll
    for (int k = 0; k < 32; k++) {
      float4 a0 = *(float4*)(&As[k][ty*8]);
      float4 a1 = *(float4*)(&As[k][ty*8+4]);
      float4 b0 = *(float4*)(&Bs[k][tx*8]);
      float4 b1 = *(float4*)(&Bs[k][tx*8+4]);
      float av[8] = {a0.x,a0.y,a0.z,a0.w,a1.x,a1.y,a1.z,a1.w};
      float bv[8] = {b0.x,b0.y,b0.z,b0.w,b1.x,b1.y,b1.z,b1.w};
      #pragma unroll
      for (int i = 0; i < 8; i++)
        #pragma unroll
        for (int q = 0; q < 8; q++) acc[i][q] += av[i]*bv[q];
    }
    __syncthreads();
  }
  const float* bop = be + ntile + tx*8;
  float4 bv0 = *(const float4*)bop;
  float4 bv1 = *(const float4*)(bop + 4);
  #pragma unroll
  for (int i = 0; i < 8; i++) {
    int m = mtile + ty*8 + i;
    float* op = encX + (size_t)m*DMn + ntile + tx*8;
    float4 v0 = make_float4(acc[i][0]+bv0.x, acc[i][1]+bv0.y,
                            acc[i][2]+bv0.z, acc[i][3]+bv0.w);
    float4 v1 = make_float4(acc[i][4]+bv1.x, acc[i][5]+bv1.y,
                            acc[i][6]+bv1.z, acc[i][7]+bv1.w);
    *(float4*)op = v0;
    *(float4*)(op + 4) = v1;
  }
}

// logits = hs @ W_out + b_out, fp32, 128x128 tile, 8x8 microtile
__global__ void __launch_bounds__(256) out_gemm(
    const float* __restrict__ hs, const float* __restrict__ Wo,
    const float* __restrict__ bo, float* __restrict__ out)
{
  __shared__ float As[32][128];
  __shared__ float Bs[32][128];
  const int tid = threadIdx.x;
  const int ntile = blockIdx.x * 128;
  const int mtile = blockIdx.y * 128;
  const int tx = tid & 15, ty = tid >> 4;
  float acc[8][8];
  #pragma unroll
  for (int i = 0; i < 8; i++)
    #pragma unroll
    for (int q = 0; q < 8; q++) acc[i][q] = 0.f;

  for (int kb = 0; kb < 16; kb++) {
    #pragma unroll
    for (int r = 0; r < 4; r++) {
      int idx = tid + r*256;
      int m = idx >> 3, kq = idx & 7;
      float4 a = *(const float4*)(hs + (size_t)(mtile + m)*512 + kb*32 + kq*4);
      As[kq*4+0][m] = a.x; As[kq*4+1][m] = a.y;
      As[kq*4+2][m] = a.z; As[kq*4+3][m] = a.w;
    }
    #pragma unroll
    for (int r = 0; r < 4; r++) {
      int idx = tid + r*256;
      int k = idx >> 5, nq = idx & 31;
      *(float4*)(&Bs[k][nq*4]) =
          *(const float4*)(Wo + (size_t)(kb*32 + k)*Vn + ntile + nq*4);
    }
    __syncthreads();
    #pragma unroll
    for (int k = 0; k < 32; k++) {
      float4 a0 = *(float4*)(&As[k][ty*8]);
      float4 a1 = *(float4*)(&As[k][ty*8+4]);
      float4 b0 = *(float4*)(&Bs[k][tx*8]);
      float4 b1 = *(float4*)(&Bs[k][tx*8+4]);
      float av[8] = {a0.x,a0.y,a0.z,a0.w,a1.x,a1.y,a1.z,a1.w};
      float bv[8] = {b0.x,b0.y,b0.z,b0.w,b1.x,b1.y,b1.z,b1.w};
      #pragma unroll
      for (int i = 0; i < 8; i++)
        #pragma unroll
        for (int q = 0; q < 8; q++) acc[i][q] += av[i]*bv[q];
    }
    __syncthreads();
  }
  const float* bop = bo + ntile + tx*8;
  float4 bv0 = *(const float4*)bop;
  float4 bv1 = *(const float4*)(bop + 4);
  #pragma unroll
  for (int i = 0; i < 8; i++) {
    int m = mtile + ty*8 + i;            // m = s*16 + b
    float* op = out + ((size_t)(m & 15)*Sn + (m >> 4))*Vn + ntile + tx*8;
    float4 v0 = make_float4(acc[i][0]+bv0.x, acc[i][1]+bv0.y,
                            acc[i][2]+bv0.z, acc[i][3]+bv0.w);
    float4 v1 = make_float4(acc[i][4]+bv1.x, acc[i][5]+bv1.y,
                            acc[i][6]+bv1.z, acc[i][7]+bv1.w);
    *(float4*)op = v0;
    *(float4*)(op + 4) = v1;
  }
}

extern "C" void kernel_launch(void* const* d_in, const int* in_sizes, int n_in,
                              void* d_out, int out_size, void* d_ws, size_t ws_size,
                              hipStream_t stream) {
  (void)in_sizes; (void)n_in; (void)out_size; (void)ws_size;
  SP p;
  p.ids    = (const int*)  d_in[0];
  p.emb    = (const float*)d_in[1];
  p.W_enc  = (const float*)d_in[2];
  p.b_enc  = (const float*)d_in[3];
  p.ln_s_g = (const float*)d_in[4];
  p.ln_s_b = (const float*)d_in[5];
  p.Wg     = (const float*)d_in[6];
  p.bg     = (const float*)d_in[7];
  p.ln_e_g = (const float*)d_in[8];
  p.ln_e_b = (const float*)d_in[9];
  p.Wi     = (const float*)d_in[10];
  p.bi     = (const float*)d_in[11];
  const float* Wo = (const float*)d_in[12];
  const float* bo = (const float*)d_in[13];

  char* ws = (char*)d_ws;
  float* WgT  = (float*)(ws + OF_WGT);
  float* WiT  = (float*)(ws + OF_WIT);
  float* encX = (float*)(ws + OF_ENCX);
  float* hs   = (float*)(ws + OF_HS);

  hipMemsetAsync(ws, 0, INIT_BYTES, stream);   // flags + states = 0

  hipLaunchKernelGGL(transpose_k, dim3(32, 16), dim3(32, 8), 0, stream,
                     p.Wg, WgT, 512, 1024);
  hipLaunchKernelGGL(transpose_k, dim3(32, 16), dim3(32, 8), 0, stream,
                     p.Wg + (size_t)512*1024, WgT + (size_t)1024*512, 512, 1024);
  hipLaunchKernelGGL(transpose_k, dim3(16, 32), dim3(32, 8), 0, stream,
                     p.Wi, WiT, 1024, 512);
  hipLaunchKernelGGL(transpose_k, dim3(16, 32), dim3(32, 8), 0, stream,
                     p.Wi + (size_t)1024*512, WiT + (size_t)512*1024, 1024, 512);

  hipLaunchKernelGGL(enc_gemm, dim3(DMn/128, 2048/128), dim3(256), 0, stream,
                     p.ids, p.emb, p.W_enc, p.b_enc, encX);

  hipLaunchKernelGGL(snn_scan, dim3(NWG), dim3(TPB), 131072, stream, p, ws);

  hipLaunchKernelGGL(out_gemm, dim3(Vn/128, 2048/128), dim3(256), 0, stream,
                     hs, Wo, bo, (float*)d_out);
}